// Round 6
// baseline (462.464 us; speedup 1.0000x reference)
//
#include <hip/hip_runtime.h>
#include <cfloat>
#include <math.h>

#define B2   2
#define BS4  4
#define NH   8
#define DH   64
#define DIM  512
#define NSEQ 1024
#define AH   16

typedef __attribute__((ext_vector_type(8))) short short8;
typedef __attribute__((ext_vector_type(4))) float floatx4;

// ---------- bf16 helpers ----------
__device__ inline unsigned short f2bf(float x) {
    unsigned int u = __float_as_uint(x);
    unsigned int r = (u + 0x7fffu + ((u >> 16) & 1u)) >> 16;
    return (unsigned short)r;
}
__device__ inline float bf2f(unsigned short h) {
    return __uint_as_float(((unsigned int)h) << 16);
}
__device__ inline void split2(float x, unsigned short& h, unsigned short& l) {
    h = f2bf(x);
    l = f2bf(x - bf2f(h));
}

// ============================================================
// NT MFMA core: C[M,N] += A[M,K] * B[N,K]^T, bf16 frags.
// SPLIT=true: A,B given as hi/lo pairs, 3 MFMAs (≈fp32 precision).
// ============================================================
template<int MT, int NT_, bool SPLIT>
__device__ inline void mfma_nt_core(
    const unsigned short* __restrict__ Ah, const unsigned short* __restrict__ Al,
    const unsigned short* __restrict__ Bh, const unsigned short* __restrict__ Bl,
    int K, int lda, int ldb, int arow, int bcol, floatx4 acc[MT][NT_])
{
    int lane = threadIdx.x & 63;
    int lr = lane & 15, lq = lane >> 4;
    for (int k0 = 0; k0 < K; k0 += 32) {
        short8 ah[MT], al[MT], bh[NT_], bl[NT_];
        #pragma unroll
        for (int mi = 0; mi < MT; ++mi) {
            size_t off = (size_t)(arow + mi * 16 + lr) * lda + k0 + lq * 8;
            ah[mi] = *(const short8*)(Ah + off);
            if (SPLIT) al[mi] = *(const short8*)(Al + off);
        }
        #pragma unroll
        for (int ni = 0; ni < NT_; ++ni) {
            size_t off = (size_t)(bcol + ni * 16 + lr) * ldb + k0 + lq * 8;
            bh[ni] = *(const short8*)(Bh + off);
            if (SPLIT) bl[ni] = *(const short8*)(Bl + off);
        }
        #pragma unroll
        for (int mi = 0; mi < MT; ++mi)
            #pragma unroll
            for (int ni = 0; ni < NT_; ++ni) {
                acc[mi][ni] = __builtin_amdgcn_mfma_f32_16x16x32_bf16(ah[mi], bh[ni], acc[mi][ni], 0, 0, 0);
                if (SPLIT) {
                    acc[mi][ni] = __builtin_amdgcn_mfma_f32_16x16x32_bf16(ah[mi], bl[ni], acc[mi][ni], 0, 0, 0);
                    acc[mi][ni] = __builtin_amdgcn_mfma_f32_16x16x32_bf16(al[mi], bh[ni], acc[mi][ni], 0, 0, 0);
                }
            }
    }
}

// ============================================================
// K1: RMSNorm + sigmoid gates; emits xn as bf16 hi/lo pairs.
// ============================================================
__global__ __launch_bounds__(256) void k_rmsnorm_gates(
    const float* __restrict__ x, const float* __restrict__ gamma,
    const float* __restrict__ wg, const float* __restrict__ bg,
    unsigned short* __restrict__ xn_h, unsigned short* __restrict__ xn_l,
    float* __restrict__ gates)
{
    int r = blockIdx.x;
    int tid = threadIdx.x;
    const float* xr = x + (size_t)r * DIM;
    float v0 = xr[tid];
    float v1 = xr[tid + 256];
    float ss = v0 * v0 + v1 * v1;
    #pragma unroll
    for (int off = 32; off > 0; off >>= 1) ss += __shfl_down(ss, off, 64);
    __shared__ float sc[4];
    __shared__ float scw[NH][4];
    if ((tid & 63) == 0) sc[tid >> 6] = ss;
    __syncthreads();
    float tot = sc[0] + sc[1] + sc[2] + sc[3];
    float rs = rsqrtf(tot * (1.0f / DIM) + 1e-5f);
    float n0 = v0 * rs * gamma[tid];
    float n1 = v1 * rs * gamma[tid + 256];
    unsigned short hh, ll;
    split2(n0, hh, ll);
    xn_h[(size_t)r * DIM + tid] = hh; xn_l[(size_t)r * DIM + tid] = ll;
    split2(n1, hh, ll);
    xn_h[(size_t)r * DIM + tid + 256] = hh; xn_l[(size_t)r * DIM + tid + 256] = ll;
    #pragma unroll
    for (int h = 0; h < NH; ++h) {
        float p = n0 * wg[h * DIM + tid] + n1 * wg[h * DIM + tid + 256];
        #pragma unroll
        for (int off = 32; off > 0; off >>= 1) p += __shfl_down(p, off, 64);
        if ((tid & 63) == 0) scw[h][tid >> 6] = p;
    }
    __syncthreads();
    if (tid < NH) {
        float g = scw[tid][0] + scw[tid][1] + scw[tid][2] + scw[tid][3] + bg[tid];
        gates[(size_t)r * NH + tid] = 1.0f / (1.0f + __expf(-g));
    }
}

// ============================================================
// Weight conversion (merged): wqkv -> split hi/lo, wout -> plain
// ============================================================
#define NQKV (3 * DIM * NH * DH)     // 786432
#define NOUT (DIM * NH * DH)         // 262144
__global__ __launch_bounds__(256) void k_cvt(
    const float* __restrict__ wqkv, const float* __restrict__ wout,
    unsigned short* __restrict__ wq_h, unsigned short* __restrict__ wq_l,
    unsigned short* __restrict__ wout_b)
{
    for (int i = blockIdx.x * 256 + threadIdx.x; i < NQKV + NOUT; i += gridDim.x * 256) {
        if (i < NQKV) {
            unsigned short hh, ll;
            split2(wqkv[i], hh, ll);
            wq_h[i] = hh; wq_l[i] = ll;
        } else {
            wout_b[i - NQKV] = f2bf(wout[i - NQKV]);
        }
    }
}

// ============================================================
// K2: QKV projection, split-bf16 MFMA. C[4096x1536]=xn*wqkv^T
// block tile 128x64 (4 waves of 64x32). Scatter epilogue.
// ============================================================
__global__ __launch_bounds__(256) void k_qkv_mfma(
    const unsigned short* __restrict__ xn_h, const unsigned short* __restrict__ xn_l,
    const unsigned short* __restrict__ wq_h, const unsigned short* __restrict__ wq_l,
    unsigned short* __restrict__ q_h, unsigned short* __restrict__ q_l,
    unsigned short* __restrict__ k_h, unsigned short* __restrict__ k_l,
    unsigned short* __restrict__ vT_b)
{
    int w = threadIdx.x >> 6;
    int am = blockIdx.y * 128 + (w & 1) * 64;
    int bn = blockIdx.x * 64 + (w >> 1) * 32;
    floatx4 acc[4][2];
    #pragma unroll
    for (int mi = 0; mi < 4; ++mi)
        #pragma unroll
        for (int ni = 0; ni < 2; ++ni) acc[mi][ni] = (floatx4){0.f, 0.f, 0.f, 0.f};
    mfma_nt_core<4, 2, true>(xn_h, xn_l, wq_h, wq_l, DIM, DIM, DIM, am, bn, acc);
    int lane = threadIdx.x & 63, lr = lane & 15, lq = lane >> 4;
    #pragma unroll
    for (int mi = 0; mi < 4; ++mi)
        #pragma unroll
        for (int ni = 0; ni < 2; ++ni)
            #pragma unroll
            for (int r = 0; r < 4; ++r) {
                int row = am + mi * 16 + lq * 4 + r;
                int col = bn + ni * 16 + lr;
                float v = acc[mi][ni][r];
                int bs = row >> 10, npos = row & 1023;
                int which = col >> 9, h = (col >> 6) & 7, d = col & 63;
                int bh = bs * 8 + h;
                if (which == 0) {
                    v *= 8.0f;  // q * sqrt(dim_head)
                    size_t idx = ((size_t)bh * NSEQ + npos) * DH + d;
                    unsigned short hh, ll; split2(v, hh, ll);
                    q_h[idx] = hh; q_l[idx] = ll;
                } else if (which == 1) {
                    size_t idx = ((size_t)bh * NSEQ + npos) * DH + d;
                    unsigned short hh, ll; split2(v, hh, ll);
                    k_h[idx] = hh; k_l[idx] = ll;
                } else {
                    vT_b[((size_t)bh * DH + d) * NSEQ + npos] = f2bf(v);
                }
            }
}

// ============================================================
// K3: sim = q*k^T per bh, split-bf16 MFMA -> d_out attn region.
// ============================================================
__global__ __launch_bounds__(256) void k_qk_mfma(
    const unsigned short* __restrict__ q_h, const unsigned short* __restrict__ q_l,
    const unsigned short* __restrict__ k_h, const unsigned short* __restrict__ k_l,
    float* __restrict__ simio)
{
    int bh = blockIdx.z;
    int w = threadIdx.x >> 6;
    int am = blockIdx.y * 128 + (w & 1) * 64;
    int bn = blockIdx.x * 64 + (w >> 1) * 32;
    const unsigned short* Ah = q_h + (size_t)bh * NSEQ * DH;
    const unsigned short* Al = q_l + (size_t)bh * NSEQ * DH;
    const unsigned short* Bh = k_h + (size_t)bh * NSEQ * DH;
    const unsigned short* Bl = k_l + (size_t)bh * NSEQ * DH;
    floatx4 acc[4][2];
    #pragma unroll
    for (int mi = 0; mi < 4; ++mi)
        #pragma unroll
        for (int ni = 0; ni < 2; ++ni) acc[mi][ni] = (floatx4){0.f, 0.f, 0.f, 0.f};
    mfma_nt_core<4, 2, true>(Ah, Al, Bh, Bl, DH, DH, DH, am, bn, acc);
    float* C = simio + ((size_t)bh << 20);
    int lane = threadIdx.x & 63, lr = lane & 15, lq = lane >> 4;
    #pragma unroll
    for (int mi = 0; mi < 4; ++mi)
        #pragma unroll
        for (int ni = 0; ni < 2; ++ni)
            #pragma unroll
            for (int r = 0; r < 4; ++r) {
                int row = am + mi * 16 + lq * 4 + r;
                int col = bn + ni * 16 + lr;
                C[(size_t)row * NSEQ + col] = acc[mi][ni][r];
            }
}

// ============================================================
// K4a (P1): pre-talk + mask + causal -> per-(channel,row) max and
// 1/sum of exp. Writes ONLY 16+16 floats per (b,i). Stats land in
// the dead xn_h/xn_l region.
// ============================================================
__global__ __launch_bounds__(256) void k_talk_reduce(
    const float* __restrict__ simio, const int* __restrict__ mask,
    const float* __restrict__ wpre,
    float* __restrict__ mx_out, float* __restrict__ inv_out)   // [b*NSEQ+i][16]
{
    const int i = blockIdx.x;
    const int b = blockIdx.y;
    const int tid = threadIdx.x;
    const int wid = tid >> 6, lane = tid & 63;
    const int j0 = tid << 2;
    const size_t cstride = (size_t)NSEQ * NSEQ;
    const size_t rbase = (size_t)(b * 16) * cstride + (size_t)i * NSEQ + j0;

    const int4 mi0 = *(const int4*)(mask + (size_t)(b * 2 + 0) * NSEQ + j0);
    const int4 mi1 = *(const int4*)(mask + (size_t)(b * 2 + 1) * NSEQ + j0);
    bool mb[2][4];
    mb[0][0] = (mi0.x != 0) && (j0 + 0 <= i);
    mb[0][1] = (mi0.y != 0) && (j0 + 1 <= i);
    mb[0][2] = (mi0.z != 0) && (j0 + 2 <= i);
    mb[0][3] = (mi0.w != 0) && (j0 + 3 <= i);
    mb[1][0] = (mi1.x != 0) && (j0 + 0 <= i);
    mb[1][1] = (mi1.y != 0) && (j0 + 1 <= i);
    mb[1][2] = (mi1.z != 0) && (j0 + 2 <= i);
    mb[1][3] = (mi1.w != 0) && (j0 + 3 <= i);

    float val[16][4];
    #pragma unroll
    for (int o = 0; o < 16; ++o) {
        val[o][0] = 0.f; val[o][1] = 0.f; val[o][2] = 0.f; val[o][3] = 0.f;
    }
    #pragma unroll
    for (int c = 0; c < 16; ++c) {
        float4 r = *(const float4*)(simio + rbase + (size_t)c * cstride);
        #pragma unroll
        for (int o = 0; o < 16; ++o) {
            float w = wpre[o * 16 + c];
            val[o][0] = fmaf(w, r.x, val[o][0]);
            val[o][1] = fmaf(w, r.y, val[o][1]);
            val[o][2] = fmaf(w, r.z, val[o][2]);
            val[o][3] = fmaf(w, r.w, val[o][3]);
        }
    }
    #pragma unroll
    for (int o = 0; o < 16; ++o) {
        const int s = o >> 3;
        #pragma unroll
        for (int u = 0; u < 4; ++u)
            if (!mb[s][u]) val[o][u] = -FLT_MAX;
    }

    __shared__ float red[16][4];
    __shared__ float finmx[16];

    #pragma unroll
    for (int o = 0; o < 16; ++o) {
        float m = fmaxf(fmaxf(val[o][0], val[o][1]), fmaxf(val[o][2], val[o][3]));
        #pragma unroll
        for (int off = 32; off > 0; off >>= 1) m = fmaxf(m, __shfl_xor(m, off, 64));
        if (lane == 0) red[o][wid] = m;
    }
    __syncthreads();
    if (tid < 16)
        finmx[tid] = fmaxf(fmaxf(red[tid][0], red[tid][1]), fmaxf(red[tid][2], red[tid][3]));
    __syncthreads();

    #pragma unroll
    for (int o = 0; o < 16; ++o) {
        float mx = finmx[o];
        float s = (__expf(val[o][0] - mx) + __expf(val[o][1] - mx))
                + (__expf(val[o][2] - mx) + __expf(val[o][3] - mx));
        #pragma unroll
        for (int off = 32; off > 0; off >>= 1) s += __shfl_xor(s, off, 64);
        if (lane == 0) red[o][wid] = s;
    }
    __syncthreads();
    if (tid < 16) {
        size_t sidx = ((size_t)b * NSEQ + i) * 16 + tid;
        mx_out[sidx] = finmx[tid];
        inv_out[sidx] = 1.0f / (red[tid][0] + red[tid][1] + red[tid][2] + red[tid][3]);
    }
}

// ============================================================
// K4b (P2): barrier-free stream. Recomputes the 16x16 mix (reads
// L3-warm), applies exp*inv via precomputed stats, NT-stores fp32
// probs in place (never re-read), post-talk -> bf16 attn2.
// ============================================================
__global__ __launch_bounds__(256) void k_talk_norm(
    float* __restrict__ simio, const int* __restrict__ mask,
    const float* __restrict__ wpre, const float* __restrict__ wpost,
    const float* __restrict__ mx_in, const float* __restrict__ inv_in,
    unsigned short* __restrict__ attn2_b)
{
    const int i = blockIdx.x;
    const int b = blockIdx.y;
    const int tid = threadIdx.x;
    const int j0 = tid << 2;
    const size_t cstride = (size_t)NSEQ * NSEQ;
    const size_t rbase = (size_t)(b * 16) * cstride + (size_t)i * NSEQ + j0;

    const int4 mi0 = *(const int4*)(mask + (size_t)(b * 2 + 0) * NSEQ + j0);
    const int4 mi1 = *(const int4*)(mask + (size_t)(b * 2 + 1) * NSEQ + j0);
    bool mb[2][4];
    mb[0][0] = (mi0.x != 0) && (j0 + 0 <= i);
    mb[0][1] = (mi0.y != 0) && (j0 + 1 <= i);
    mb[0][2] = (mi0.z != 0) && (j0 + 2 <= i);
    mb[0][3] = (mi0.w != 0) && (j0 + 3 <= i);
    mb[1][0] = (mi1.x != 0) && (j0 + 0 <= i);
    mb[1][1] = (mi1.y != 0) && (j0 + 1 <= i);
    mb[1][2] = (mi1.z != 0) && (j0 + 2 <= i);
    mb[1][3] = (mi1.w != 0) && (j0 + 3 <= i);

    float val[16][4];
    #pragma unroll
    for (int o = 0; o < 16; ++o) {
        val[o][0] = 0.f; val[o][1] = 0.f; val[o][2] = 0.f; val[o][3] = 0.f;
    }
    #pragma unroll
    for (int c = 0; c < 16; ++c) {
        float4 r = *(const float4*)(simio + rbase + (size_t)c * cstride);
        #pragma unroll
        for (int o = 0; o < 16; ++o) {
            float w = wpre[o * 16 + c];
            val[o][0] = fmaf(w, r.x, val[o][0]);
            val[o][1] = fmaf(w, r.y, val[o][1]);
            val[o][2] = fmaf(w, r.z, val[o][2]);
            val[o][3] = fmaf(w, r.w, val[o][3]);
        }
    }
    #pragma unroll
    for (int o = 0; o < 16; ++o) {
        const int s = o >> 3;
        #pragma unroll
        for (int u = 0; u < 4; ++u)
            if (!mb[s][u]) val[o][u] = -FLT_MAX;
    }

    const size_t sidx = ((size_t)b * NSEQ + i) * 16;
    // exp * inv, NT-store probs (floatx4 = clang ext vector, accepted by the builtin)
    #pragma unroll
    for (int o = 0; o < 16; ++o) {
        float mx = mx_in[sidx + o];
        float inv = inv_in[sidx + o];
        val[o][0] = __expf(val[o][0] - mx) * inv;
        val[o][1] = __expf(val[o][1] - mx) * inv;
        val[o][2] = __expf(val[o][2] - mx) * inv;
        val[o][3] = __expf(val[o][3] - mx) * inv;
        floatx4 st = {val[o][0], val[o][1], val[o][2], val[o][3]};
        __builtin_nontemporal_store(st, (floatx4*)(simio + rbase + (size_t)o * cstride));
    }

    // post talking-heads -> bf16 attn2 (cacheable: re-read by av)
    #pragma unroll
    for (int o = 0; o < 16; ++o) {
        float a0 = 0.f, a1 = 0.f, a2 = 0.f, a3 = 0.f;
        #pragma unroll
        for (int c = 0; c < 16; ++c) {
            float w = wpost[o * 16 + c];
            a0 = fmaf(w, val[c][0], a0);
            a1 = fmaf(w, val[c][1], a1);
            a2 = fmaf(w, val[c][2], a2);
            a3 = fmaf(w, val[c][3], a3);
        }
        unsigned long long pk = (unsigned long long)f2bf(a0)
                              | ((unsigned long long)f2bf(a1) << 16)
                              | ((unsigned long long)f2bf(a2) << 32)
                              | ((unsigned long long)f2bf(a3) << 48);
        *(unsigned long long*)(attn2_b + rbase + (size_t)o * cstride) = pk;
    }
}

// ============================================================
// K5: gated = (attn2 @ v) * gate, plain bf16 MFMA (NT with vT).
// ============================================================
__global__ __launch_bounds__(256) void k_av_mfma(
    const unsigned short* __restrict__ attn2_b, const unsigned short* __restrict__ vT_b,
    const float* __restrict__ gates, unsigned short* __restrict__ gated_b)
{
    int bh = blockIdx.y;
    int bs = bh >> 3, h = bh & 7;
    int w = threadIdx.x >> 6;
    int am = blockIdx.x * 64 + (w & 1) * 32;
    int bn = (w >> 1) * 32;
    const unsigned short* Ah = attn2_b + ((size_t)bh << 20);
    const unsigned short* Bh = vT_b + (size_t)bh * DH * NSEQ;
    floatx4 acc[2][2];
    #pragma unroll
    for (int mi = 0; mi < 2; ++mi)
        #pragma unroll
        for (int ni = 0; ni < 2; ++ni) acc[mi][ni] = (floatx4){0.f, 0.f, 0.f, 0.f};
    mfma_nt_core<2, 2, false>(Ah, nullptr, Bh, nullptr, NSEQ, NSEQ, NSEQ, am, bn, acc);
    int lane = threadIdx.x & 63, lr = lane & 15, lq = lane >> 4;
    #pragma unroll
    for (int mi = 0; mi < 2; ++mi)
        #pragma unroll
        for (int ni = 0; ni < 2; ++ni)
            #pragma unroll
            for (int r = 0; r < 4; ++r) {
                int i = am + mi * 16 + lq * 4 + r;
                int d = bn + ni * 16 + lr;
                float g = gates[((size_t)bs * NSEQ + i) * NH + h];
                gated_b[((size_t)bs * NSEQ + i) * DIM + h * DH + d] = f2bf(acc[mi][ni][r] * g);
            }
}

// ============================================================
// K6: out = gated @ wout^T, plain bf16 MFMA.
// ============================================================
__global__ __launch_bounds__(256) void k_out_mfma(
    const unsigned short* __restrict__ gated_b, const unsigned short* __restrict__ wout_b,
    float* __restrict__ out)
{
    int w = threadIdx.x >> 6;
    int am = blockIdx.y * 64 + (w & 1) * 32;
    int bn = blockIdx.x * 64 + (w >> 1) * 32;
    floatx4 acc[2][2];
    #pragma unroll
    for (int mi = 0; mi < 2; ++mi)
        #pragma unroll
        for (int ni = 0; ni < 2; ++ni) acc[mi][ni] = (floatx4){0.f, 0.f, 0.f, 0.f};
    mfma_nt_core<2, 2, false>(gated_b, nullptr, wout_b, nullptr, DIM, DIM, DIM, am, bn, acc);
    int lane = threadIdx.x & 63, lr = lane & 15, lq = lane >> 4;
    #pragma unroll
    for (int mi = 0; mi < 2; ++mi)
        #pragma unroll
        for (int ni = 0; ni < 2; ++ni)
            #pragma unroll
            for (int r = 0; r < 4; ++r) {
                int row = am + mi * 16 + lq * 4 + r;
                int col = bn + ni * 16 + lr;
                out[(size_t)row * DIM + col] = acc[mi][ni][r];
            }
}

// ============================================================
extern "C" void kernel_launch(void* const* d_in, const int* in_sizes, int n_in,
                              void* d_out, int out_size, void* d_ws, size_t ws_size,
                              hipStream_t stream)
{
    (void)in_sizes; (void)n_in; (void)out_size; (void)ws_size;

    const float* x     = (const float*)d_in[0];
    const int*   mask  = (const int*)  d_in[1];
    const float* gamma = (const float*)d_in[2];
    const float* wqkv  = (const float*)d_in[3];
    const float* wg    = (const float*)d_in[4];
    const float* bg    = (const float*)d_in[5];
    const float* wpre  = (const float*)d_in[6];
    const float* wpost = (const float*)d_in[7];
    const float* wout  = (const float*)d_in[8];

    float* out      = (float*)d_out;
    float* attn_out = out + (size_t)BS4 * NSEQ * DIM;  // sim lives here, softmaxed in place

    // workspace layout (bytes)
    char* ws = (char*)d_ws;
    unsigned short* xn_h    = (unsigned short*)(ws);                 //  4 MB (dead after qkv -> reused for stats)
    unsigned short* xn_l    = (unsigned short*)(ws + 4194304);       //  4 MB
    unsigned short* wq_h    = (unsigned short*)(ws + 8388608);       //  1.5 MB
    unsigned short* wq_l    = (unsigned short*)(ws + 9961472);       //  1.5 MB
    unsigned short* wout_b  = (unsigned short*)(ws + 11534336);      //  0.5 MB
    float*          gates   = (float*)         (ws + 12058624);      //  128 KB
    unsigned short* q_h     = (unsigned short*)(ws + 12189696);      //  4 MB
    unsigned short* q_l     = (unsigned short*)(ws + 16384000);      //  4 MB
    unsigned short* k_h     = (unsigned short*)(ws + 20578304);      //  4 MB
    unsigned short* k_l     = (unsigned short*)(ws + 24772608);      //  4 MB
    unsigned short* vT_b    = (unsigned short*)(ws + 28966912);      //  4 MB
    unsigned short* gated_b = (unsigned short*)(ws + 33161216);      //  4 MB
    unsigned short* attn2_b = (unsigned short*)(ws + 37355520);      // 64 MB

    // softmax stats reuse the dead xn region (qkv_mfma has completed by then)
    float* mx_stats  = (float*)xn_h;       // 2*1024*16*4 = 128 KB
    float* inv_stats = (float*)xn_l;       // 128 KB

    k_rmsnorm_gates<<<dim3(BS4 * NSEQ), dim3(256), 0, stream>>>(x, gamma, wg, bg, xn_h, xn_l, gates);
    k_cvt<<<dim3(1024), dim3(256), 0, stream>>>(wqkv, wout, wq_h, wq_l, wout_b);
    k_qkv_mfma<<<dim3(24, 32), dim3(256), 0, stream>>>(xn_h, xn_l, wq_h, wq_l, q_h, q_l, k_h, k_l, vT_b);
    k_qk_mfma<<<dim3(16, 8, 32), dim3(256), 0, stream>>>(q_h, q_l, k_h, k_l, attn_out);
    k_talk_reduce<<<dim3(NSEQ, B2), dim3(256), 0, stream>>>(attn_out, mask, wpre, mx_stats, inv_stats);
    k_talk_norm<<<dim3(NSEQ, B2), dim3(256), 0, stream>>>(attn_out, mask, wpre, wpost, mx_stats, inv_stats, attn2_b);
    k_av_mfma<<<dim3(16, 32), dim3(256), 0, stream>>>(attn2_b, vT_b, gates, gated_b);
    k_out_mfma<<<dim3(8, 64), dim3(256), 0, stream>>>(gated_b, wout_b, out);
}

// Round 7
// 406.239 us; speedup vs baseline: 1.1384x; 1.1384x over previous
//
#include <hip/hip_runtime.h>
#include <cfloat>
#include <math.h>

#define B2   2
#define BS4  4
#define NH   8
#define DH   64
#define DIM  512
#define NSEQ 1024
#define AH   16

typedef __attribute__((ext_vector_type(8))) short short8;
typedef __attribute__((ext_vector_type(4))) float floatx4;

// ---------- bf16 helpers ----------
__device__ inline unsigned short f2bf(float x) {
    unsigned int u = __float_as_uint(x);
    unsigned int r = (u + 0x7fffu + ((u >> 16) & 1u)) >> 16;
    return (unsigned short)r;
}
__device__ inline float bf2f(unsigned short h) {
    return __uint_as_float(((unsigned int)h) << 16);
}
__device__ inline void split2(float x, unsigned short& h, unsigned short& l) {
    h = f2bf(x);
    l = f2bf(x - bf2f(h));
}

// ============================================================
// NT MFMA core: C[M,N] += A[M,K] * B[N,K]^T, bf16 frags.
// SPLIT=true: A,B given as hi/lo pairs, 3 MFMAs (≈fp32 precision).
// ============================================================
template<int MT, int NT_, bool SPLIT>
__device__ inline void mfma_nt_core(
    const unsigned short* __restrict__ Ah, const unsigned short* __restrict__ Al,
    const unsigned short* __restrict__ Bh, const unsigned short* __restrict__ Bl,
    int K, int lda, int ldb, int arow, int bcol, floatx4 acc[MT][NT_])
{
    int lane = threadIdx.x & 63;
    int lr = lane & 15, lq = lane >> 4;
    for (int k0 = 0; k0 < K; k0 += 32) {
        short8 ah[MT], al[MT], bh[NT_], bl[NT_];
        #pragma unroll
        for (int mi = 0; mi < MT; ++mi) {
            size_t off = (size_t)(arow + mi * 16 + lr) * lda + k0 + lq * 8;
            ah[mi] = *(const short8*)(Ah + off);
            if (SPLIT) al[mi] = *(const short8*)(Al + off);
        }
        #pragma unroll
        for (int ni = 0; ni < NT_; ++ni) {
            size_t off = (size_t)(bcol + ni * 16 + lr) * ldb + k0 + lq * 8;
            bh[ni] = *(const short8*)(Bh + off);
            if (SPLIT) bl[ni] = *(const short8*)(Bl + off);
        }
        #pragma unroll
        for (int mi = 0; mi < MT; ++mi)
            #pragma unroll
            for (int ni = 0; ni < NT_; ++ni) {
                acc[mi][ni] = __builtin_amdgcn_mfma_f32_16x16x32_bf16(ah[mi], bh[ni], acc[mi][ni], 0, 0, 0);
                if (SPLIT) {
                    acc[mi][ni] = __builtin_amdgcn_mfma_f32_16x16x32_bf16(ah[mi], bl[ni], acc[mi][ni], 0, 0, 0);
                    acc[mi][ni] = __builtin_amdgcn_mfma_f32_16x16x32_bf16(al[mi], bh[ni], acc[mi][ni], 0, 0, 0);
                }
            }
    }
}

// ============================================================
// K1: RMSNorm + sigmoid gates; emits xn as bf16 hi/lo pairs.
// ============================================================
__global__ __launch_bounds__(256) void k_rmsnorm_gates(
    const float* __restrict__ x, const float* __restrict__ gamma,
    const float* __restrict__ wg, const float* __restrict__ bg,
    unsigned short* __restrict__ xn_h, unsigned short* __restrict__ xn_l,
    float* __restrict__ gates)
{
    int r = blockIdx.x;
    int tid = threadIdx.x;
    const float* xr = x + (size_t)r * DIM;
    float v0 = xr[tid];
    float v1 = xr[tid + 256];
    float ss = v0 * v0 + v1 * v1;
    #pragma unroll
    for (int off = 32; off > 0; off >>= 1) ss += __shfl_down(ss, off, 64);
    __shared__ float sc[4];
    __shared__ float scw[NH][4];
    if ((tid & 63) == 0) sc[tid >> 6] = ss;
    __syncthreads();
    float tot = sc[0] + sc[1] + sc[2] + sc[3];
    float rs = rsqrtf(tot * (1.0f / DIM) + 1e-5f);
    float n0 = v0 * rs * gamma[tid];
    float n1 = v1 * rs * gamma[tid + 256];
    unsigned short hh, ll;
    split2(n0, hh, ll);
    xn_h[(size_t)r * DIM + tid] = hh; xn_l[(size_t)r * DIM + tid] = ll;
    split2(n1, hh, ll);
    xn_h[(size_t)r * DIM + tid + 256] = hh; xn_l[(size_t)r * DIM + tid + 256] = ll;
    #pragma unroll
    for (int h = 0; h < NH; ++h) {
        float p = n0 * wg[h * DIM + tid] + n1 * wg[h * DIM + tid + 256];
        #pragma unroll
        for (int off = 32; off > 0; off >>= 1) p += __shfl_down(p, off, 64);
        if ((tid & 63) == 0) scw[h][tid >> 6] = p;
    }
    __syncthreads();
    if (tid < NH) {
        float g = scw[tid][0] + scw[tid][1] + scw[tid][2] + scw[tid][3] + bg[tid];
        gates[(size_t)r * NH + tid] = 1.0f / (1.0f + __expf(-g));
    }
}

// ============================================================
// Weight conversion (merged): wqkv -> split hi/lo, wout -> plain
// ============================================================
#define NQKV (3 * DIM * NH * DH)     // 786432
#define NOUT (DIM * NH * DH)         // 262144
__global__ __launch_bounds__(256) void k_cvt(
    const float* __restrict__ wqkv, const float* __restrict__ wout,
    unsigned short* __restrict__ wq_h, unsigned short* __restrict__ wq_l,
    unsigned short* __restrict__ wout_b)
{
    for (int i = blockIdx.x * 256 + threadIdx.x; i < NQKV + NOUT; i += gridDim.x * 256) {
        if (i < NQKV) {
            unsigned short hh, ll;
            split2(wqkv[i], hh, ll);
            wq_h[i] = hh; wq_l[i] = ll;
        } else {
            wout_b[i - NQKV] = f2bf(wout[i - NQKV]);
        }
    }
}

// ============================================================
// K2: QKV projection, split-bf16 MFMA. C[4096x1536]=xn*wqkv^T
// block tile 128x64 (4 waves of 64x32). Scatter epilogue.
// ============================================================
__global__ __launch_bounds__(256) void k_qkv_mfma(
    const unsigned short* __restrict__ xn_h, const unsigned short* __restrict__ xn_l,
    const unsigned short* __restrict__ wq_h, const unsigned short* __restrict__ wq_l,
    unsigned short* __restrict__ q_h, unsigned short* __restrict__ q_l,
    unsigned short* __restrict__ k_h, unsigned short* __restrict__ k_l,
    unsigned short* __restrict__ vT_b)
{
    int w = threadIdx.x >> 6;
    int am = blockIdx.y * 128 + (w & 1) * 64;
    int bn = blockIdx.x * 64 + (w >> 1) * 32;
    floatx4 acc[4][2];
    #pragma unroll
    for (int mi = 0; mi < 4; ++mi)
        #pragma unroll
        for (int ni = 0; ni < 2; ++ni) acc[mi][ni] = (floatx4){0.f, 0.f, 0.f, 0.f};
    mfma_nt_core<4, 2, true>(xn_h, xn_l, wq_h, wq_l, DIM, DIM, DIM, am, bn, acc);
    int lane = threadIdx.x & 63, lr = lane & 15, lq = lane >> 4;
    #pragma unroll
    for (int mi = 0; mi < 4; ++mi)
        #pragma unroll
        for (int ni = 0; ni < 2; ++ni)
            #pragma unroll
            for (int r = 0; r < 4; ++r) {
                int row = am + mi * 16 + lq * 4 + r;
                int col = bn + ni * 16 + lr;
                float v = acc[mi][ni][r];
                int bs = row >> 10, npos = row & 1023;
                int which = col >> 9, h = (col >> 6) & 7, d = col & 63;
                int bh = bs * 8 + h;
                if (which == 0) {
                    v *= 8.0f;  // q * sqrt(dim_head)
                    size_t idx = ((size_t)bh * NSEQ + npos) * DH + d;
                    unsigned short hh, ll; split2(v, hh, ll);
                    q_h[idx] = hh; q_l[idx] = ll;
                } else if (which == 1) {
                    size_t idx = ((size_t)bh * NSEQ + npos) * DH + d;
                    unsigned short hh, ll; split2(v, hh, ll);
                    k_h[idx] = hh; k_l[idx] = ll;
                } else {
                    vT_b[((size_t)bh * DH + d) * NSEQ + npos] = f2bf(v);
                }
            }
}

// ============================================================
// K3: sim = q*k^T per bh, split-bf16 MFMA.
// Writes CHANNEL-INTERLEAVED sim_ws[b][i][c][j] (c = s*8+h).
// All 16 channels of row i live in one contiguous 64 KB window.
// ============================================================
__global__ __launch_bounds__(256) void k_qk_mfma(
    const unsigned short* __restrict__ q_h, const unsigned short* __restrict__ q_l,
    const unsigned short* __restrict__ k_h, const unsigned short* __restrict__ k_l,
    float* __restrict__ sim_ws)
{
    int bh = blockIdx.z;
    int b_true = bh >> 4;
    int c = ((bh >> 3) & 1) * 8 + (bh & 7);
    int w = threadIdx.x >> 6;
    int am = blockIdx.y * 128 + (w & 1) * 64;
    int bn = blockIdx.x * 64 + (w >> 1) * 32;
    const unsigned short* Ah = q_h + (size_t)bh * NSEQ * DH;
    const unsigned short* Al = q_l + (size_t)bh * NSEQ * DH;
    const unsigned short* Bh = k_h + (size_t)bh * NSEQ * DH;
    const unsigned short* Bl = k_l + (size_t)bh * NSEQ * DH;
    floatx4 acc[4][2];
    #pragma unroll
    for (int mi = 0; mi < 4; ++mi)
        #pragma unroll
        for (int ni = 0; ni < 2; ++ni) acc[mi][ni] = (floatx4){0.f, 0.f, 0.f, 0.f};
    mfma_nt_core<4, 2, true>(Ah, Al, Bh, Bl, DH, DH, DH, am, bn, acc);
    int lane = threadIdx.x & 63, lr = lane & 15, lq = lane >> 4;
    #pragma unroll
    for (int mi = 0; mi < 4; ++mi)
        #pragma unroll
        for (int ni = 0; ni < 2; ++ni)
            #pragma unroll
            for (int r = 0; r < 4; ++r) {
                int row = am + mi * 16 + lq * 4 + r;
                int col = bn + ni * 16 + lr;
                sim_ws[((size_t)(b_true * NSEQ + row) * 16 + c) * NSEQ + col] = acc[mi][ni][r];
            }
}

// ============================================================
// K4 (fused, interleaved): pre-talk + mask + causal + softmax +
// post-talk. Block = 256 thr, one (b,i); thread owns 4 j.
// Reads its 16-channel row from ONE contiguous 64 KB window.
// Probs -> d_out (strided, NT). attn2 bf16 -> in place over the
// first half of this row's own sim_ws region (no cross-block hazard).
// 4 barriers total. c streamed outermost (R3 spill lesson).
// ============================================================
__global__ __launch_bounds__(256) void k_talk(
    float* __restrict__ sim_ws, const int* __restrict__ mask,
    const float* __restrict__ wpre, const float* __restrict__ wpost,
    float* __restrict__ probs_out)
{
    const int i = blockIdx.x;
    const int b = blockIdx.y;
    const int tid = threadIdx.x;
    const int wid = tid >> 6, lane = tid & 63;
    const int j0 = tid << 2;
    const size_t cstride = (size_t)NSEQ * NSEQ;
    float* simrow = sim_ws + (size_t)(b * NSEQ + i) * (16 * NSEQ);

    const int4 mi0 = *(const int4*)(mask + (size_t)(b * 2 + 0) * NSEQ + j0);
    const int4 mi1 = *(const int4*)(mask + (size_t)(b * 2 + 1) * NSEQ + j0);
    bool mb[2][4];
    mb[0][0] = (mi0.x != 0) && (j0 + 0 <= i);
    mb[0][1] = (mi0.y != 0) && (j0 + 1 <= i);
    mb[0][2] = (mi0.z != 0) && (j0 + 2 <= i);
    mb[0][3] = (mi0.w != 0) && (j0 + 3 <= i);
    mb[1][0] = (mi1.x != 0) && (j0 + 0 <= i);
    mb[1][1] = (mi1.y != 0) && (j0 + 1 <= i);
    mb[1][2] = (mi1.z != 0) && (j0 + 2 <= i);
    mb[1][3] = (mi1.w != 0) && (j0 + 3 <= i);

    // ---- pre talking-heads, c streamed outermost ----
    float val[16][4];
    #pragma unroll
    for (int o = 0; o < 16; ++o) {
        val[o][0] = 0.f; val[o][1] = 0.f; val[o][2] = 0.f; val[o][3] = 0.f;
    }
    #pragma unroll
    for (int c = 0; c < 16; ++c) {
        float4 r = *(const float4*)(simrow + c * NSEQ + j0);
        #pragma unroll
        for (int o = 0; o < 16; ++o) {
            float w = wpre[o * 16 + c];
            val[o][0] = fmaf(w, r.x, val[o][0]);
            val[o][1] = fmaf(w, r.y, val[o][1]);
            val[o][2] = fmaf(w, r.z, val[o][2]);
            val[o][3] = fmaf(w, r.w, val[o][3]);
        }
    }
    #pragma unroll
    for (int o = 0; o < 16; ++o) {
        const int s = o >> 3;
        #pragma unroll
        for (int u = 0; u < 4; ++u)
            if (!mb[s][u]) val[o][u] = -FLT_MAX;
    }

    __shared__ float red[16][4];
    __shared__ float finmx[16];
    __shared__ float fininv[16];

    // ---- batched block max (2 barriers) ----
    #pragma unroll
    for (int o = 0; o < 16; ++o) {
        float m = fmaxf(fmaxf(val[o][0], val[o][1]), fmaxf(val[o][2], val[o][3]));
        #pragma unroll
        for (int off = 32; off > 0; off >>= 1) m = fmaxf(m, __shfl_xor(m, off, 64));
        if (lane == 0) red[o][wid] = m;
    }
    __syncthreads();
    if (tid < 16)
        finmx[tid] = fmaxf(fmaxf(red[tid][0], red[tid][1]), fmaxf(red[tid][2], red[tid][3]));
    __syncthreads();

    // ---- exp + batched block sum (2 barriers) ----
    #pragma unroll
    for (int o = 0; o < 16; ++o) {
        float mx = finmx[o];
        val[o][0] = __expf(val[o][0] - mx);
        val[o][1] = __expf(val[o][1] - mx);
        val[o][2] = __expf(val[o][2] - mx);
        val[o][3] = __expf(val[o][3] - mx);
        float s = (val[o][0] + val[o][1]) + (val[o][2] + val[o][3]);
        #pragma unroll
        for (int off = 32; off > 0; off >>= 1) s += __shfl_xor(s, off, 64);
        if (lane == 0) red[o][wid] = s;
    }
    __syncthreads();
    if (tid < 16)
        fininv[tid] = 1.0f / (red[tid][0] + red[tid][1] + red[tid][2] + red[tid][3]);
    __syncthreads();

    // ---- normalize + NT-store probs (output 1, [b*16+o][i][j]) ----
    #pragma unroll
    for (int o = 0; o < 16; ++o) {
        float inv = fininv[o];
        val[o][0] *= inv; val[o][1] *= inv; val[o][2] *= inv; val[o][3] *= inv;
        floatx4 st = {val[o][0], val[o][1], val[o][2], val[o][3]};
        __builtin_nontemporal_store(st,
            (floatx4*)(probs_out + (size_t)(b * 16 + o) * cstride + (size_t)i * NSEQ + j0));
    }

    // ---- post talking-heads -> bf16 attn2, in place over own row ----
    unsigned short* a2row = (unsigned short*)simrow;   // first 32 KB of this row's 64 KB region
    #pragma unroll
    for (int o = 0; o < 16; ++o) {
        float a0 = 0.f, a1 = 0.f, a2 = 0.f, a3 = 0.f;
        #pragma unroll
        for (int c = 0; c < 16; ++c) {
            float w = wpost[o * 16 + c];
            a0 = fmaf(w, val[c][0], a0);
            a1 = fmaf(w, val[c][1], a1);
            a2 = fmaf(w, val[c][2], a2);
            a3 = fmaf(w, val[c][3], a3);
        }
        unsigned long long pk = (unsigned long long)f2bf(a0)
                              | ((unsigned long long)f2bf(a1) << 16)
                              | ((unsigned long long)f2bf(a2) << 32)
                              | ((unsigned long long)f2bf(a3) << 48);
        *(unsigned long long*)(a2row + o * NSEQ + j0) = pk;
    }
}

// ============================================================
// K5: gated = (attn2 @ v) * gate, plain bf16 MFMA (NT with vT).
// attn2 read from interleaved region: row i stride = 32768 ushorts.
// ============================================================
__global__ __launch_bounds__(256) void k_av_mfma(
    const unsigned short* __restrict__ attn2_il, const unsigned short* __restrict__ vT_b,
    const float* __restrict__ gates, unsigned short* __restrict__ gated_b)
{
    int bh = blockIdx.y;
    int bs = bh >> 3, h = bh & 7;
    int b_true = bh >> 4;
    int c = ((bh >> 3) & 1) * 8 + (bh & 7);
    int w = threadIdx.x >> 6;
    int am = blockIdx.x * 64 + (w & 1) * 32;
    int bn = (w >> 1) * 32;
    // attn2(i,j) at attn2_il[(b_true*NSEQ + i)*32768 + c*NSEQ + j]
    const unsigned short* Ah = attn2_il + (size_t)b_true * NSEQ * 32768 + (size_t)c * NSEQ;
    const unsigned short* Bh = vT_b + (size_t)bh * DH * NSEQ;
    floatx4 acc[2][2];
    #pragma unroll
    for (int mi = 0; mi < 2; ++mi)
        #pragma unroll
        for (int ni = 0; ni < 2; ++ni) acc[mi][ni] = (floatx4){0.f, 0.f, 0.f, 0.f};
    mfma_nt_core<2, 2, false>(Ah, nullptr, Bh, nullptr, NSEQ, 32768, NSEQ, am, bn, acc);
    int lane = threadIdx.x & 63, lr = lane & 15, lq = lane >> 4;
    #pragma unroll
    for (int mi = 0; mi < 2; ++mi)
        #pragma unroll
        for (int ni = 0; ni < 2; ++ni)
            #pragma unroll
            for (int r = 0; r < 4; ++r) {
                int i = am + mi * 16 + lq * 4 + r;
                int d = bn + ni * 16 + lr;
                float g = gates[((size_t)bs * NSEQ + i) * NH + h];
                gated_b[((size_t)bs * NSEQ + i) * DIM + h * DH + d] = f2bf(acc[mi][ni][r] * g);
            }
}

// ============================================================
// K6: out = gated @ wout^T, plain bf16 MFMA.
// ============================================================
__global__ __launch_bounds__(256) void k_out_mfma(
    const unsigned short* __restrict__ gated_b, const unsigned short* __restrict__ wout_b,
    float* __restrict__ out)
{
    int w = threadIdx.x >> 6;
    int am = blockIdx.y * 64 + (w & 1) * 32;
    int bn = blockIdx.x * 64 + (w >> 1) * 32;
    floatx4 acc[2][2];
    #pragma unroll
    for (int mi = 0; mi < 2; ++mi)
        #pragma unroll
        for (int ni = 0; ni < 2; ++ni) acc[mi][ni] = (floatx4){0.f, 0.f, 0.f, 0.f};
    mfma_nt_core<2, 2, false>(gated_b, nullptr, wout_b, nullptr, DIM, DIM, DIM, am, bn, acc);
    int lane = threadIdx.x & 63, lr = lane & 15, lq = lane >> 4;
    #pragma unroll
    for (int mi = 0; mi < 2; ++mi)
        #pragma unroll
        for (int ni = 0; ni < 2; ++ni)
            #pragma unroll
            for (int r = 0; r < 4; ++r) {
                int row = am + mi * 16 + lq * 4 + r;
                int col = bn + ni * 16 + lr;
                out[(size_t)row * DIM + col] = acc[mi][ni][r];
            }
}

// ============================================================
extern "C" void kernel_launch(void* const* d_in, const int* in_sizes, int n_in,
                              void* d_out, int out_size, void* d_ws, size_t ws_size,
                              hipStream_t stream)
{
    (void)in_sizes; (void)n_in; (void)out_size; (void)ws_size;

    const float* x     = (const float*)d_in[0];
    const int*   mask  = (const int*)  d_in[1];
    const float* gamma = (const float*)d_in[2];
    const float* wqkv  = (const float*)d_in[3];
    const float* wg    = (const float*)d_in[4];
    const float* bg    = (const float*)d_in[5];
    const float* wpre  = (const float*)d_in[6];
    const float* wpost = (const float*)d_in[7];
    const float* wout  = (const float*)d_in[8];

    float* out       = (float*)d_out;
    float* probs_out = out + (size_t)BS4 * NSEQ * DIM;   // output 1: [bs][h][i][j]

    // workspace layout (bytes)
    char* ws = (char*)d_ws;
    unsigned short* xn_h    = (unsigned short*)(ws);                 //  4 MB
    unsigned short* xn_l    = (unsigned short*)(ws + 4194304);       //  4 MB
    unsigned short* wq_h    = (unsigned short*)(ws + 8388608);       //  1.5 MB
    unsigned short* wq_l    = (unsigned short*)(ws + 9961472);       //  1.5 MB
    unsigned short* wout_b  = (unsigned short*)(ws + 11534336);      //  0.5 MB
    float*          gates   = (float*)         (ws + 12058624);      //  128 KB
    unsigned short* q_h     = (unsigned short*)(ws + 12189696);      //  4 MB
    unsigned short* q_l     = (unsigned short*)(ws + 16384000);      //  4 MB
    unsigned short* k_h     = (unsigned short*)(ws + 20578304);      //  4 MB
    unsigned short* k_l     = (unsigned short*)(ws + 24772608);      //  4 MB
    unsigned short* vT_b    = (unsigned short*)(ws + 28966912);      //  4 MB
    unsigned short* gated_b = (unsigned short*)(ws + 33161216);      //  4 MB
    float*          sim_ws  = (float*)         (ws + 37355520);      // 128 MB interleaved [b][i][c][j]
    // total ~165.6 MB

    k_rmsnorm_gates<<<dim3(BS4 * NSEQ), dim3(256), 0, stream>>>(x, gamma, wg, bg, xn_h, xn_l, gates);
    k_cvt<<<dim3(1024), dim3(256), 0, stream>>>(wqkv, wout, wq_h, wq_l, wout_b);
    k_qkv_mfma<<<dim3(24, 32), dim3(256), 0, stream>>>(xn_h, xn_l, wq_h, wq_l, q_h, q_l, k_h, k_l, vT_b);
    k_qk_mfma<<<dim3(16, 8, 32), dim3(256), 0, stream>>>(q_h, q_l, k_h, k_l, sim_ws);
    k_talk<<<dim3(NSEQ, B2), dim3(256), 0, stream>>>(sim_ws, mask, wpre, wpost, probs_out);
    k_av_mfma<<<dim3(16, 32), dim3(256), 0, stream>>>((unsigned short*)sim_ws, vT_b, gates, gated_b);
    k_out_mfma<<<dim3(8, 64), dim3(256), 0, stream>>>(gated_b, wout_b, out);
}

// Round 8
// 404.291 us; speedup vs baseline: 1.1439x; 1.0048x over previous
//
#include <hip/hip_runtime.h>
#include <cfloat>
#include <math.h>

#define B2   2
#define BS4  4
#define NH   8
#define DH   64
#define DIM  512
#define NSEQ 1024
#define AH   16

typedef __attribute__((ext_vector_type(8))) short short8;
typedef __attribute__((ext_vector_type(4))) float floatx4;

// ---------- bf16 helpers ----------
__device__ inline unsigned short f2bf(float x) {
    unsigned int u = __float_as_uint(x);
    unsigned int r = (u + 0x7fffu + ((u >> 16) & 1u)) >> 16;
    return (unsigned short)r;
}
__device__ inline float bf2f(unsigned short h) {
    return __uint_as_float(((unsigned int)h) << 16);
}
__device__ inline void split2(float x, unsigned short& h, unsigned short& l) {
    h = f2bf(x);
    l = f2bf(x - bf2f(h));
}

// ============================================================
// NT MFMA core: C[M,N] += A[M,K] * B[N,K]^T, bf16 frags.
// SPLIT=true: A,B given as hi/lo pairs, 3 MFMAs (≈fp32 precision).
// ============================================================
template<int MT, int NT_, bool SPLIT>
__device__ inline void mfma_nt_core(
    const unsigned short* __restrict__ Ah, const unsigned short* __restrict__ Al,
    const unsigned short* __restrict__ Bh, const unsigned short* __restrict__ Bl,
    int K, int lda, int ldb, int arow, int bcol, floatx4 acc[MT][NT_])
{
    int lane = threadIdx.x & 63;
    int lr = lane & 15, lq = lane >> 4;
    for (int k0 = 0; k0 < K; k0 += 32) {
        short8 ah[MT], al[MT], bh[NT_], bl[NT_];
        #pragma unroll
        for (int mi = 0; mi < MT; ++mi) {
            size_t off = (size_t)(arow + mi * 16 + lr) * lda + k0 + lq * 8;
            ah[mi] = *(const short8*)(Ah + off);
            if (SPLIT) al[mi] = *(const short8*)(Al + off);
        }
        #pragma unroll
        for (int ni = 0; ni < NT_; ++ni) {
            size_t off = (size_t)(bcol + ni * 16 + lr) * ldb + k0 + lq * 8;
            bh[ni] = *(const short8*)(Bh + off);
            if (SPLIT) bl[ni] = *(const short8*)(Bl + off);
        }
        #pragma unroll
        for (int mi = 0; mi < MT; ++mi)
            #pragma unroll
            for (int ni = 0; ni < NT_; ++ni) {
                acc[mi][ni] = __builtin_amdgcn_mfma_f32_16x16x32_bf16(ah[mi], bh[ni], acc[mi][ni], 0, 0, 0);
                if (SPLIT) {
                    acc[mi][ni] = __builtin_amdgcn_mfma_f32_16x16x32_bf16(ah[mi], bl[ni], acc[mi][ni], 0, 0, 0);
                    acc[mi][ni] = __builtin_amdgcn_mfma_f32_16x16x32_bf16(al[mi], bh[ni], acc[mi][ni], 0, 0, 0);
                }
            }
    }
}

// ============================================================
// K1: RMSNorm + sigmoid gates; emits xn as bf16 hi/lo pairs.
// ============================================================
__global__ __launch_bounds__(256) void k_rmsnorm_gates(
    const float* __restrict__ x, const float* __restrict__ gamma,
    const float* __restrict__ wg, const float* __restrict__ bg,
    unsigned short* __restrict__ xn_h, unsigned short* __restrict__ xn_l,
    float* __restrict__ gates)
{
    int r = blockIdx.x;
    int tid = threadIdx.x;
    const float* xr = x + (size_t)r * DIM;
    float v0 = xr[tid];
    float v1 = xr[tid + 256];
    float ss = v0 * v0 + v1 * v1;
    #pragma unroll
    for (int off = 32; off > 0; off >>= 1) ss += __shfl_down(ss, off, 64);
    __shared__ float sc[4];
    __shared__ float scw[NH][4];
    if ((tid & 63) == 0) sc[tid >> 6] = ss;
    __syncthreads();
    float tot = sc[0] + sc[1] + sc[2] + sc[3];
    float rs = rsqrtf(tot * (1.0f / DIM) + 1e-5f);
    float n0 = v0 * rs * gamma[tid];
    float n1 = v1 * rs * gamma[tid + 256];
    unsigned short hh, ll;
    split2(n0, hh, ll);
    xn_h[(size_t)r * DIM + tid] = hh; xn_l[(size_t)r * DIM + tid] = ll;
    split2(n1, hh, ll);
    xn_h[(size_t)r * DIM + tid + 256] = hh; xn_l[(size_t)r * DIM + tid + 256] = ll;
    #pragma unroll
    for (int h = 0; h < NH; ++h) {
        float p = n0 * wg[h * DIM + tid] + n1 * wg[h * DIM + tid + 256];
        #pragma unroll
        for (int off = 32; off > 0; off >>= 1) p += __shfl_down(p, off, 64);
        if ((tid & 63) == 0) scw[h][tid >> 6] = p;
    }
    __syncthreads();
    if (tid < NH) {
        float g = scw[tid][0] + scw[tid][1] + scw[tid][2] + scw[tid][3] + bg[tid];
        gates[(size_t)r * NH + tid] = 1.0f / (1.0f + __expf(-g));
    }
}

// ============================================================
// Weight conversion (merged): wqkv -> split hi/lo, wout -> plain
// ============================================================
#define NQKV (3 * DIM * NH * DH)     // 786432
#define NOUT (DIM * NH * DH)         // 262144
__global__ __launch_bounds__(256) void k_cvt(
    const float* __restrict__ wqkv, const float* __restrict__ wout,
    unsigned short* __restrict__ wq_h, unsigned short* __restrict__ wq_l,
    unsigned short* __restrict__ wout_b)
{
    for (int i = blockIdx.x * 256 + threadIdx.x; i < NQKV + NOUT; i += gridDim.x * 256) {
        if (i < NQKV) {
            unsigned short hh, ll;
            split2(wqkv[i], hh, ll);
            wq_h[i] = hh; wq_l[i] = ll;
        } else {
            wout_b[i - NQKV] = f2bf(wout[i - NQKV]);
        }
    }
}

// ============================================================
// K2: QKV projection, split-bf16 MFMA. C[4096x1536]=xn*wqkv^T
// block tile 128x64 (4 waves of 64x32). `which` is block-uniform
// (bx<8: q, 8..15: k, 16..23: v). v-blocks use an LDS-staged
// transposed epilogue (fixes the 2B x 64-lane scatter).
// ============================================================
__global__ __launch_bounds__(256) void k_qkv_mfma(
    const unsigned short* __restrict__ xn_h, const unsigned short* __restrict__ xn_l,
    const unsigned short* __restrict__ wq_h, const unsigned short* __restrict__ wq_l,
    unsigned short* __restrict__ q_h, unsigned short* __restrict__ q_l,
    unsigned short* __restrict__ k_h, unsigned short* __restrict__ k_l,
    unsigned short* __restrict__ vT_b)
{
    __shared__ unsigned short vs[64][132];   // [d][npos_local], pad to kill conflicts
    int w = threadIdx.x >> 6;
    int bx = blockIdx.x;
    int am = blockIdx.y * 128 + (w & 1) * 64;
    int bn = bx * 64 + (w >> 1) * 32;
    floatx4 acc[4][2];
    #pragma unroll
    for (int mi = 0; mi < 4; ++mi)
        #pragma unroll
        for (int ni = 0; ni < 2; ++ni) acc[mi][ni] = (floatx4){0.f, 0.f, 0.f, 0.f};
    mfma_nt_core<4, 2, true>(xn_h, xn_l, wq_h, wq_l, DIM, DIM, DIM, am, bn, acc);
    int tid = threadIdx.x;
    int lane = tid & 63, lr = lane & 15, lq = lane >> 4;

    if (bx < 16) {
        // ---- q or k: direct stores (32B segments), split hi/lo ----
        const bool isq = (bx < 8);
        unsigned short* dh = isq ? q_h : k_h;
        unsigned short* dl = isq ? q_l : k_l;
        const float scale = isq ? 8.0f : 1.0f;   // q * sqrt(dim_head)
        #pragma unroll
        for (int mi = 0; mi < 4; ++mi)
            #pragma unroll
            for (int ni = 0; ni < 2; ++ni)
                #pragma unroll
                for (int r = 0; r < 4; ++r) {
                    int row = am + mi * 16 + lq * 4 + r;
                    int col = bn + ni * 16 + lr;
                    int bs = row >> 10, npos = row & 1023;
                    int h = (col >> 6) & 7, d = col & 63;
                    size_t idx = (((size_t)(bs * 8 + h)) * NSEQ + npos) * DH + d;
                    unsigned short hh, ll;
                    split2(acc[mi][ni][r] * scale, hh, ll);
                    dh[idx] = hh; dl[idx] = ll;
                }
    } else {
        // ---- v: stage transposed bf16 tile in LDS, coalesced store ----
        const int h = bx - 16;                    // uniform per block
        const int bs = (blockIdx.y * 128) >> 10;  // uniform (128 | 1024)
        const int bh = bs * 8 + h;
        const int npos_base = (blockIdx.y * 128) & 1023;
        #pragma unroll
        for (int mi = 0; mi < 4; ++mi)
            #pragma unroll
            for (int ni = 0; ni < 2; ++ni)
                #pragma unroll
                for (int r = 0; r < 4; ++r) {
                    int nl = (w & 1) * 64 + mi * 16 + lq * 4 + r;   // npos_local 0..127
                    int dl2 = (w >> 1) * 32 + ni * 16 + lr;         // d 0..63
                    vs[dl2][nl] = f2bf(acc[mi][ni][r]);
                }
        __syncthreads();
        int d = tid >> 2;            // 0..63
        int sub = tid & 3;
        unsigned short* dst = vT_b + ((size_t)bh * DH + d) * NSEQ + npos_base;
        #pragma unroll
        for (int it = 0; it < 4; ++it) {
            int nl = sub * 8 + it * 32;
            // 8 ushorts = 16 B per lane; 4 consecutive lanes cover 64 B of one d-row
            *(ulonglong2*)(dst + nl) = *(ulonglong2*)&vs[d][nl];
        }
    }
}

// ============================================================
// K3: sim = q*k^T per bh, split-bf16 MFMA.
// Writes CHANNEL-INTERLEAVED sim_ws[b][i][c][j] (c = s*8+h) via an
// LDS-staged coalesced epilogue (256B segments vs 64B direct).
// ============================================================
__global__ __launch_bounds__(256) void k_qk_mfma(
    const unsigned short* __restrict__ q_h, const unsigned short* __restrict__ q_l,
    const unsigned short* __restrict__ k_h, const unsigned short* __restrict__ k_l,
    float* __restrict__ sim_ws)
{
    __shared__ float cs[128][68];    // 128 rows x 64 cols, pad 68 -> <=2-way banks
    int bh = blockIdx.z;
    int b_true = bh >> 4;
    int c = ((bh >> 3) & 1) * 8 + (bh & 7);
    int w = threadIdx.x >> 6;
    int am = blockIdx.y * 128 + (w & 1) * 64;
    int bn = blockIdx.x * 64 + (w >> 1) * 32;
    const unsigned short* Ah = q_h + (size_t)bh * NSEQ * DH;
    const unsigned short* Al = q_l + (size_t)bh * NSEQ * DH;
    const unsigned short* Bh = k_h + (size_t)bh * NSEQ * DH;
    const unsigned short* Bl = k_l + (size_t)bh * NSEQ * DH;
    floatx4 acc[4][2];
    #pragma unroll
    for (int mi = 0; mi < 4; ++mi)
        #pragma unroll
        for (int ni = 0; ni < 2; ++ni) acc[mi][ni] = (floatx4){0.f, 0.f, 0.f, 0.f};
    mfma_nt_core<4, 2, true>(Ah, Al, Bh, Bl, DH, DH, DH, am, bn, acc);

    int tid = threadIdx.x;
    int lane = tid & 63, lr = lane & 15, lq = lane >> 4;
    // stage into LDS
    #pragma unroll
    for (int mi = 0; mi < 4; ++mi)
        #pragma unroll
        for (int ni = 0; ni < 2; ++ni)
            #pragma unroll
            for (int r = 0; r < 4; ++r) {
                int lrow = (w & 1) * 64 + mi * 16 + lq * 4 + r;
                int lcol = (w >> 1) * 32 + ni * 16 + lr;
                cs[lrow][lcol] = acc[mi][ni][r];
            }
    __syncthreads();
    // coalesced store: 16 lanes cover one 256B row-segment
    int trow = tid >> 4;          // 0..15
    int tcol = (tid & 15) * 4;    // 0..60
    int am0 = blockIdx.y * 128;
    int bn0 = blockIdx.x * 64;
    #pragma unroll
    for (int it = 0; it < 8; ++it) {
        int row = it * 16 + trow;
        float4 v4 = *(float4*)&cs[row][tcol];
        size_t gaddr = ((size_t)(b_true * NSEQ + am0 + row) * 16 + c) * NSEQ + bn0 + tcol;
        *(float4*)(sim_ws + gaddr) = v4;
    }
}

// ============================================================
// K4 (fused, interleaved): pre-talk + mask + causal + softmax +
// post-talk. Block = 256 thr, one (b,i); thread owns 4 j.
// Reads its 16-channel row from ONE contiguous 64 KB window.
// Probs -> d_out (strided, NT). attn2 bf16 -> in place over the
// first half of this row's own sim_ws region. 4 barriers total.
// ============================================================
__global__ __launch_bounds__(256) void k_talk(
    float* __restrict__ sim_ws, const int* __restrict__ mask,
    const float* __restrict__ wpre, const float* __restrict__ wpost,
    float* __restrict__ probs_out)
{
    const int i = blockIdx.x;
    const int b = blockIdx.y;
    const int tid = threadIdx.x;
    const int wid = tid >> 6, lane = tid & 63;
    const int j0 = tid << 2;
    const size_t cstride = (size_t)NSEQ * NSEQ;
    float* simrow = sim_ws + (size_t)(b * NSEQ + i) * (16 * NSEQ);

    const int4 mi0 = *(const int4*)(mask + (size_t)(b * 2 + 0) * NSEQ + j0);
    const int4 mi1 = *(const int4*)(mask + (size_t)(b * 2 + 1) * NSEQ + j0);
    bool mb[2][4];
    mb[0][0] = (mi0.x != 0) && (j0 + 0 <= i);
    mb[0][1] = (mi0.y != 0) && (j0 + 1 <= i);
    mb[0][2] = (mi0.z != 0) && (j0 + 2 <= i);
    mb[0][3] = (mi0.w != 0) && (j0 + 3 <= i);
    mb[1][0] = (mi1.x != 0) && (j0 + 0 <= i);
    mb[1][1] = (mi1.y != 0) && (j0 + 1 <= i);
    mb[1][2] = (mi1.z != 0) && (j0 + 2 <= i);
    mb[1][3] = (mi1.w != 0) && (j0 + 3 <= i);

    // ---- pre talking-heads, c streamed outermost ----
    float val[16][4];
    #pragma unroll
    for (int o = 0; o < 16; ++o) {
        val[o][0] = 0.f; val[o][1] = 0.f; val[o][2] = 0.f; val[o][3] = 0.f;
    }
    #pragma unroll
    for (int c = 0; c < 16; ++c) {
        float4 r = *(const float4*)(simrow + c * NSEQ + j0);
        #pragma unroll
        for (int o = 0; o < 16; ++o) {
            float w = wpre[o * 16 + c];
            val[o][0] = fmaf(w, r.x, val[o][0]);
            val[o][1] = fmaf(w, r.y, val[o][1]);
            val[o][2] = fmaf(w, r.z, val[o][2]);
            val[o][3] = fmaf(w, r.w, val[o][3]);
        }
    }
    #pragma unroll
    for (int o = 0; o < 16; ++o) {
        const int s = o >> 3;
        #pragma unroll
        for (int u = 0; u < 4; ++u)
            if (!mb[s][u]) val[o][u] = -FLT_MAX;
    }

    __shared__ float red[16][4];
    __shared__ float finmx[16];
    __shared__ float fininv[16];

    // ---- batched block max (2 barriers) ----
    #pragma unroll
    for (int o = 0; o < 16; ++o) {
        float m = fmaxf(fmaxf(val[o][0], val[o][1]), fmaxf(val[o][2], val[o][3]));
        #pragma unroll
        for (int off = 32; off > 0; off >>= 1) m = fmaxf(m, __shfl_xor(m, off, 64));
        if (lane == 0) red[o][wid] = m;
    }
    __syncthreads();
    if (tid < 16)
        finmx[tid] = fmaxf(fmaxf(red[tid][0], red[tid][1]), fmaxf(red[tid][2], red[tid][3]));
    __syncthreads();

    // ---- exp + batched block sum (2 barriers) ----
    #pragma unroll
    for (int o = 0; o < 16; ++o) {
        float mx = finmx[o];
        val[o][0] = __expf(val[o][0] - mx);
        val[o][1] = __expf(val[o][1] - mx);
        val[o][2] = __expf(val[o][2] - mx);
        val[o][3] = __expf(val[o][3] - mx);
        float s = (val[o][0] + val[o][1]) + (val[o][2] + val[o][3]);
        #pragma unroll
        for (int off = 32; off > 0; off >>= 1) s += __shfl_xor(s, off, 64);
        if (lane == 0) red[o][wid] = s;
    }
    __syncthreads();
    if (tid < 16)
        fininv[tid] = 1.0f / (red[tid][0] + red[tid][1] + red[tid][2] + red[tid][3]);
    __syncthreads();

    // ---- normalize + NT-store probs (output 1, [b*16+o][i][j]) ----
    #pragma unroll
    for (int o = 0; o < 16; ++o) {
        float inv = fininv[o];
        val[o][0] *= inv; val[o][1] *= inv; val[o][2] *= inv; val[o][3] *= inv;
        floatx4 st = {val[o][0], val[o][1], val[o][2], val[o][3]};
        __builtin_nontemporal_store(st,
            (floatx4*)(probs_out + (size_t)(b * 16 + o) * cstride + (size_t)i * NSEQ + j0));
    }

    // ---- post talking-heads -> bf16 attn2, in place over own row ----
    unsigned short* a2row = (unsigned short*)simrow;   // first 32 KB of this row's 64 KB region
    #pragma unroll
    for (int o = 0; o < 16; ++o) {
        float a0 = 0.f, a1 = 0.f, a2 = 0.f, a3 = 0.f;
        #pragma unroll
        for (int c = 0; c < 16; ++c) {
            float w = wpost[o * 16 + c];
            a0 = fmaf(w, val[c][0], a0);
            a1 = fmaf(w, val[c][1], a1);
            a2 = fmaf(w, val[c][2], a2);
            a3 = fmaf(w, val[c][3], a3);
        }
        unsigned long long pk = (unsigned long long)f2bf(a0)
                              | ((unsigned long long)f2bf(a1) << 16)
                              | ((unsigned long long)f2bf(a2) << 32)
                              | ((unsigned long long)f2bf(a3) << 48);
        *(unsigned long long*)(a2row + o * NSEQ + j0) = pk;
    }
}

// ============================================================
// K5: gated = (attn2 @ v) * gate, plain bf16 MFMA (NT with vT).
// attn2 read from interleaved region: row i stride = 32768 ushorts.
// ============================================================
__global__ __launch_bounds__(256) void k_av_mfma(
    const unsigned short* __restrict__ attn2_il, const unsigned short* __restrict__ vT_b,
    const float* __restrict__ gates, unsigned short* __restrict__ gated_b)
{
    int bh = blockIdx.y;
    int bs = bh >> 3, h = bh & 7;
    int b_true = bh >> 4;
    int c = ((bh >> 3) & 1) * 8 + (bh & 7);
    int w = threadIdx.x >> 6;
    int am = blockIdx.x * 64 + (w & 1) * 32;
    int bn = (w >> 1) * 32;
    const unsigned short* Ah = attn2_il + (size_t)b_true * NSEQ * 32768 + (size_t)c * NSEQ;
    const unsigned short* Bh = vT_b + (size_t)bh * DH * NSEQ;
    floatx4 acc[2][2];
    #pragma unroll
    for (int mi = 0; mi < 2; ++mi)
        #pragma unroll
        for (int ni = 0; ni < 2; ++ni) acc[mi][ni] = (floatx4){0.f, 0.f, 0.f, 0.f};
    mfma_nt_core<2, 2, false>(Ah, nullptr, Bh, nullptr, NSEQ, 32768, NSEQ, am, bn, acc);
    int lane = threadIdx.x & 63, lr = lane & 15, lq = lane >> 4;
    #pragma unroll
    for (int mi = 0; mi < 2; ++mi)
        #pragma unroll
        for (int ni = 0; ni < 2; ++ni)
            #pragma unroll
            for (int r = 0; r < 4; ++r) {
                int i = am + mi * 16 + lq * 4 + r;
                int d = bn + ni * 16 + lr;
                float g = gates[((size_t)bs * NSEQ + i) * NH + h];
                gated_b[((size_t)bs * NSEQ + i) * DIM + h * DH + d] = f2bf(acc[mi][ni][r] * g);
            }
}

// ============================================================
// K6: out = gated @ wout^T, plain bf16 MFMA.
// ============================================================
__global__ __launch_bounds__(256) void k_out_mfma(
    const unsigned short* __restrict__ gated_b, const unsigned short* __restrict__ wout_b,
    float* __restrict__ out)
{
    int w = threadIdx.x >> 6;
    int am = blockIdx.y * 64 + (w & 1) * 32;
    int bn = blockIdx.x * 64 + (w >> 1) * 32;
    floatx4 acc[2][2];
    #pragma unroll
    for (int mi = 0; mi < 2; ++mi)
        #pragma unroll
        for (int ni = 0; ni < 2; ++ni) acc[mi][ni] = (floatx4){0.f, 0.f, 0.f, 0.f};
    mfma_nt_core<2, 2, false>(gated_b, nullptr, wout_b, nullptr, DIM, DIM, DIM, am, bn, acc);
    int lane = threadIdx.x & 63, lr = lane & 15, lq = lane >> 4;
    #pragma unroll
    for (int mi = 0; mi < 2; ++mi)
        #pragma unroll
        for (int ni = 0; ni < 2; ++ni)
            #pragma unroll
            for (int r = 0; r < 4; ++r) {
                int row = am + mi * 16 + lq * 4 + r;
                int col = bn + ni * 16 + lr;
                out[(size_t)row * DIM + col] = acc[mi][ni][r];
            }
}

// ============================================================
extern "C" void kernel_launch(void* const* d_in, const int* in_sizes, int n_in,
                              void* d_out, int out_size, void* d_ws, size_t ws_size,
                              hipStream_t stream)
{
    (void)in_sizes; (void)n_in; (void)out_size; (void)ws_size;

    const float* x     = (const float*)d_in[0];
    const int*   mask  = (const int*)  d_in[1];
    const float* gamma = (const float*)d_in[2];
    const float* wqkv  = (const float*)d_in[3];
    const float* wg    = (const float*)d_in[4];
    const float* bg    = (const float*)d_in[5];
    const float* wpre  = (const float*)d_in[6];
    const float* wpost = (const float*)d_in[7];
    const float* wout  = (const float*)d_in[8];

    float* out       = (float*)d_out;
    float* probs_out = out + (size_t)BS4 * NSEQ * DIM;   // output 1: [bs][h][i][j]

    // workspace layout (bytes)
    char* ws = (char*)d_ws;
    unsigned short* xn_h    = (unsigned short*)(ws);                 //  4 MB
    unsigned short* xn_l    = (unsigned short*)(ws + 4194304);       //  4 MB
    unsigned short* wq_h    = (unsigned short*)(ws + 8388608);       //  1.5 MB
    unsigned short* wq_l    = (unsigned short*)(ws + 9961472);       //  1.5 MB
    unsigned short* wout_b  = (unsigned short*)(ws + 11534336);      //  0.5 MB
    float*          gates   = (float*)         (ws + 12058624);      //  128 KB
    unsigned short* q_h     = (unsigned short*)(ws + 12189696);      //  4 MB
    unsigned short* q_l     = (unsigned short*)(ws + 16384000);      //  4 MB
    unsigned short* k_h     = (unsigned short*)(ws + 20578304);      //  4 MB
    unsigned short* k_l     = (unsigned short*)(ws + 24772608);      //  4 MB
    unsigned short* vT_b    = (unsigned short*)(ws + 28966912);      //  4 MB
    unsigned short* gated_b = (unsigned short*)(ws + 33161216);      //  4 MB
    float*          sim_ws  = (float*)         (ws + 37355520);      // 128 MB interleaved [b][i][c][j]

    k_rmsnorm_gates<<<dim3(BS4 * NSEQ), dim3(256), 0, stream>>>(x, gamma, wg, bg, xn_h, xn_l, gates);
    k_cvt<<<dim3(1024), dim3(256), 0, stream>>>(wqkv, wout, wq_h, wq_l, wout_b);
    k_qkv_mfma<<<dim3(24, 32), dim3(256), 0, stream>>>(xn_h, xn_l, wq_h, wq_l, q_h, q_l, k_h, k_l, vT_b);
    k_qk_mfma<<<dim3(16, 8, 32), dim3(256), 0, stream>>>(q_h, q_l, k_h, k_l, sim_ws);
    k_talk<<<dim3(NSEQ, B2), dim3(256), 0, stream>>>(sim_ws, mask, wpre, wpost, probs_out);
    k_av_mfma<<<dim3(16, 32), dim3(256), 0, stream>>>((unsigned short*)sim_ws, vT_b, gates, gated_b);
    k_out_mfma<<<dim3(8, 64), dim3(256), 0, stream>>>(gated_b, wout_b, out);
}